// Round 9
// baseline (266.525 us; speedup 1.0000x reference)
//
#include <hip/hip_runtime.h>
#include <hip/hip_bf16.h>

#define BN   2
#define SEQ  2048
#define DIM  1024
#define NH   16
#define HD   64
#define D4   4096
#define MAXS 4096

using bf16 = __hip_bfloat16;
typedef __bf16 bf16x8 __attribute__((ext_vector_type(8)));
typedef float  f32x4  __attribute__((ext_vector_type(4)));

__device__ __forceinline__ float bf2f(bf16 v){ return __bfloat162float(v); }
__device__ __forceinline__ bf16  f2bf(float v){ return __float2bfloat16(v); }
__device__ __forceinline__ float silu_f(float v){
  const float e = __expf(-v);
  return v * __builtin_amdgcn_rcpf(1.f + e);
}

__device__ __forceinline__ void async16(void* lds, const void* g){
  __builtin_amdgcn_global_load_lds((const __attribute__((address_space(1))) void*)g,
                                   (__attribute__((address_space(3))) void*)lds, 16, 0, 0);
}
__device__ __forceinline__ f32x4 mfma16(bf16x8 a, bf16x8 b, f32x4 c){
  return __builtin_amdgcn_mfma_f32_16x16x32_bf16(a, b, c, 0, 0, 0);
}

// ---------------- fp32 -> bf16 convert (3 arrays, 1 launch) ----------------
__global__ __launch_bounds__(256) void f2bk3(
    const float* __restrict__ a, bf16* __restrict__ ao, int na,
    const float* __restrict__ b, bf16* __restrict__ bo, int nb,
    const float* __restrict__ c, bf16* __restrict__ co)
{
  int i = (blockIdx.x * 256 + threadIdx.x) * 4;
  const float* in; bf16* out;
  if (i < na){ in = a; out = ao; }
  else if (i < na + nb){ in = b; out = bo; i -= na; }
  else { in = c; out = co; i -= na + nb; }
  const float4 v = *(const float4*)(in + i);
  bf16 t0 = f2bf(v.x), t1 = f2bf(v.y), t2 = f2bf(v.z), t3 = f2bf(v.w);
  ushort4 o;
  o.x = *(unsigned short*)&t0; o.y = *(unsigned short*)&t1;
  o.z = *(unsigned short*)&t2; o.w = *(unsigned short*)&t3;
  *(ushort4*)((unsigned short*)out + i) = o;
}

// ---------------- GEMM1: C = silu(A @ W^T + bias); v-tiles write transposed vt ----------------
template<int NTOT>
__global__ __launch_bounds__(256) void gemm_bt(
    const bf16* __restrict__ A, const bf16* __restrict__ W,
    const float* __restrict__ bias, bf16* __restrict__ outb, bf16* __restrict__ vt)
{
  constexpr int K = DIM;
  const int ntiles = NTOT / 128;
  const int m0 = (int)(blockIdx.x / ntiles) * 128;
  const int n0 = (int)(blockIdx.x % ntiles) * 128;
  __shared__ bf16 Al[128*32];
  __shared__ bf16 Bl[128*32];
  const int tid = threadIdx.x, wave = tid>>6, lane = tid&63;
  const int quad = lane>>4, l16 = lane&15;
  const int srow = lane>>2;
  const int sg   = ((lane&3) ^ ((lane>>3)&3)) * 8;
  const int wm = (wave>>1)*64, wn = (wave&1)*64;
  const int rkey = ((l16>>1)&3);

  f32x4 acc[4][4];
  #pragma unroll
  for (int i=0;i<4;i++)
    #pragma unroll
    for (int j=0;j<4;j++) acc[i][j] = (f32x4){0.f,0.f,0.f,0.f};

  const bf16* aB = A + m0*K;
  const bf16* wB = W + n0*K;

  for (int k0 = 0; k0 < K; k0 += 32){
    async16(&Al[wave*1024      ], aB + (wave*32      + srow)*K + k0 + sg);
    async16(&Al[wave*1024 + 512], aB + (wave*32 + 16 + srow)*K + k0 + sg);
    async16(&Bl[wave*1024      ], wB + (wave*32      + srow)*K + k0 + sg);
    async16(&Bl[wave*1024 + 512], wB + (wave*32 + 16 + srow)*K + k0 + sg);
    __syncthreads();
    bf16x8 af[4], bv[4];
    #pragma unroll
    for (int mt=0;mt<4;mt++) af[mt] = *(const bf16x8*)&Al[(wm+mt*16+l16)*32 + (quad ^ rkey)*8];
    #pragma unroll
    for (int nt=0;nt<4;nt++) bv[nt] = *(const bf16x8*)&Bl[(wn+nt*16+l16)*32 + (quad ^ rkey)*8];
    #pragma unroll
    for (int mt=0;mt<4;mt++)
      #pragma unroll
      for (int nt=0;nt<4;nt++)
        acc[mt][nt] = mfma16(af[mt], bv[nt], acc[mt][nt]);
    __syncthreads();
  }

  const bool vtile = (NTOT == 4096) && (n0 >= 3*DIM);
  if (!vtile){
    #pragma unroll
    for (int mt=0;mt<4;mt++){
      #pragma unroll
      for (int nt=0;nt<4;nt++){
        const int row = m0 + wm + mt*16 + quad*4;
        const int col = n0 + wn + nt*16 + l16;
        const float bvv = bias[col];
        #pragma unroll
        for (int r=0;r<4;r++){
          float v = silu_f(acc[mt][nt][r] + bvv);
          outb[(row+r)*NTOT + col] = f2bf(v);
        }
      }
    }
  } else {
    #pragma unroll
    for (int mt=0;mt<4;mt++){
      #pragma unroll
      for (int nt=0;nt<4;nt++){
        const int row = m0 + wm + mt*16 + quad*4;
        const int colg = n0 + wn + nt*16 + l16;
        const float bvv = bias[colg];
        const int col = colg - 3*DIM;
        const int hh = col >> 6, d = col & 63;
        const int bb = row >> 11, sl = row & 2047;
        ushort4 o;
        float v0 = silu_f(acc[mt][nt][0] + bvv);
        float v1 = silu_f(acc[mt][nt][1] + bvv);
        float v2 = silu_f(acc[mt][nt][2] + bvv);
        float v3 = silu_f(acc[mt][nt][3] + bvv);
        bf16 t0=f2bf(v0), t1=f2bf(v1), t2=f2bf(v2), t3=f2bf(v3);
        o.x=*(unsigned short*)&t0; o.y=*(unsigned short*)&t1;
        o.z=*(unsigned short*)&t2; o.w=*(unsigned short*)&t3;
        *(ushort4*)&vt[((bb*NH + hh)*HD + d)*SEQ + sl] = o;
      }
    }
  }
}

// ---------------- GEMM2: z = A @ W^T + bias + resid, 128x64 tile, fp32 out ----------------
__global__ __launch_bounds__(256) void gemm_bt2(
    const bf16* __restrict__ A, const bf16* __restrict__ W,
    const float* __restrict__ bias, const float* __restrict__ resid,
    float* __restrict__ outf)
{
  constexpr int K = DIM, NTOT = DIM;
  const int ntiles = NTOT / 64;
  const int m0 = (int)(blockIdx.x / ntiles) * 128;
  const int n0 = (int)(blockIdx.x % ntiles) * 64;
  __shared__ bf16 Al[128*32];
  __shared__ bf16 Bl[64*32];
  const int tid = threadIdx.x, wave = tid>>6, lane = tid&63;
  const int quad = lane>>4, l16 = lane&15;
  const int srow = lane>>2;
  const int sg   = ((lane&3) ^ ((lane>>3)&3)) * 8;
  const int wm = wave*32;
  const int rkey = ((l16>>1)&3);

  f32x4 acc[2][4];
  #pragma unroll
  for (int i=0;i<2;i++)
    #pragma unroll
    for (int j=0;j<4;j++) acc[i][j] = (f32x4){0.f,0.f,0.f,0.f};

  const bf16* aB = A + m0*K;
  const bf16* wB = W + n0*K;

  for (int k0 = 0; k0 < K; k0 += 32){
    async16(&Al[wave*1024      ], aB + (wave*32      + srow)*K + k0 + sg);
    async16(&Al[wave*1024 + 512], aB + (wave*32 + 16 + srow)*K + k0 + sg);
    async16(&Bl[wave*512       ], wB + (wave*16      + srow)*K + k0 + sg);
    __syncthreads();
    bf16x8 af[2], bv[4];
    #pragma unroll
    for (int mt=0;mt<2;mt++) af[mt] = *(const bf16x8*)&Al[(wm+mt*16+l16)*32 + (quad ^ rkey)*8];
    #pragma unroll
    for (int nt=0;nt<4;nt++) bv[nt] = *(const bf16x8*)&Bl[(nt*16+l16)*32 + (quad ^ rkey)*8];
    #pragma unroll
    for (int mt=0;mt<2;mt++)
      #pragma unroll
      for (int nt=0;nt<4;nt++)
        acc[mt][nt] = mfma16(af[mt], bv[nt], acc[mt][nt]);
    __syncthreads();
  }

  #pragma unroll
  for (int mt=0;mt<2;mt++){
    #pragma unroll
    for (int nt=0;nt<4;nt++){
      const int row = m0 + wm + mt*16 + quad*4;
      const int col = n0 + nt*16 + l16;
      const float bvv = bias[col];
      #pragma unroll
      for (int r=0;r<4;r++){
        outf[(row+r)*NTOT + col] = acc[mt][nt][r] + bvv + resid[(row+r)*NTOT + col];
      }
    }
  }
}

// ---------------- attention: register-direct K/V, barrier-free chunk loop ----------------
// 512 blocks: (b,h)[32] x pair{p,15-p}[8] x k-parity[2]; bid%8 pins (b,h) to an XCD.
// q-tile 128 (32 rows/wave). K frags read straight from h (A-layout = contiguous d),
// V^T frags straight from vt (B-layout = contiguous s). LDS: only P round-trip +
// a 12KB pw window staged once (single __syncthreads per block).
__global__ __launch_bounds__(256) void attn(
    const bf16* __restrict__ h, const bf16* __restrict__ vt,
    const float* __restrict__ pw, float* __restrict__ yp0, float* __restrict__ yp1)
{
  const int bid  = blockIdx.x;
  const int xcd  = bid & 7;
  const int idx  = bid >> 3;                   // 0..63
  const int g    = ((idx >> 4) << 3) | xcd;    // (b,head) 0..31, 4 per XCD
  const int slot = idx & 15;
  const int p    = slot >> 1;                  // pair 0..7
  const int ksp  = slot & 1;                   // k-chunk parity
  const int hh = g & 15, b = g >> 4;
  float* __restrict__ yp = ksp ? yp1 : yp0;

  __shared__ float pwl[3072];      // pw[2048 .. 5120) = window for d in [-2047, 1024)
  __shared__ bf16 Pl[4][32*72];    // per-wave P [qrow_local][kpos_local], stride 72

  const int tid = threadIdx.x, wave = tid>>6, lane = tid&63;
  const int quad = lane>>4, l16 = lane&15;

  // stage pw window once (768 x 16B slots, all in-bounds: 2048+3072 <= 8191)
  #pragma unroll
  for (int rr=0;rr<3;rr++)
    async16(&pwl[(rr*256 + tid)*4], pw + 2048 + (rr*256 + tid)*4);
  __syncthreads();

  const bf16* kgb = h + b*SEQ*D4 + 2*DIM + hh*HD;
  const bf16* vgb = vt + (b*NH + hh)*HD*SEQ;

  #pragma unroll
  for (int pass = 0; pass < 2; ++pass){
    const int qt = pass ? (15 - p) : p;
    const int q0 = qt * 128;

    // Q fragments: rows q0 + wave*32 + mt*16 + l16, d = ks*32 + quad*8
    bf16x8 qf[2][2];
    #pragma unroll
    for (int mt=0;mt<2;mt++){
      const bf16* qb = h + (b*SEQ + q0 + wave*32 + mt*16 + l16)*D4 + DIM + hh*HD;
      qf[mt][0] = *(const bf16x8*)(qb + quad*8);
      qf[mt][1] = *(const bf16x8*)(qb + 32 + quad*8);
    }

    f32x4 oacc[2][4];
    #pragma unroll
    for (int mt=0;mt<2;mt++)
      #pragma unroll
      for (int nt=0;nt<4;nt++) oacc[mt][nt] = (f32x4){0.f,0.f,0.f,0.f};

    const int nch = 2*(qt+1);          // 64-chunks in [0, q0+128)
    for (int ic = ksp; ic < nch; ic += 2){
      const int k0 = ic * 64;

      // S^T = K @ Q^T: kf from global (A-frag: kpos=nt*16+l16, d contiguous)
      f32x4 sacc[2][4];
      #pragma unroll
      for (int mt=0;mt<2;mt++)
        #pragma unroll
        for (int nt=0;nt<4;nt++) sacc[mt][nt] = (f32x4){0.f,0.f,0.f,0.f};
      #pragma unroll
      for (int ks=0;ks<2;ks++){
        #pragma unroll
        for (int nt=0;nt<4;nt++){
          bf16x8 kf = *(const bf16x8*)(kgb + (k0 + nt*16 + l16)*D4 + ks*32 + quad*8);
          sacc[0][nt] = mfma16(kf, qf[0][ks], sacc[0][nt]);
          sacc[1][nt] = mfma16(kf, qf[1][ks], sacc[1][nt]);
        }
      }

      // bias + silu (+mask only on diagonal-crossing frags); lane: qrow=l16(+mt*16),
      // kpos = nt*16+quad*4+r (4 consecutive) -> b64 spill into Pl.
      #pragma unroll
      for (int mt=0;mt<2;mt++){
        const int ibase = q0 + wave*32 + mt*16 + l16;     // absolute i for this lane
        const bool need_mask = (k0 + 63 > q0 + wave*32 + mt*16);  // wave-uniform
        #pragma unroll
        for (int nt=0;nt<4;nt++){
          const int jbase = k0 + nt*16 + quad*4;          // absolute j for r=0
          const int dd0 = jbase - ibase;                  // d for r=0
          bf16 tb[4];
          if (need_mask){
            #pragma unroll
            for (int r=0;r<4;r++){
              const float bias = pwl[dd0 + r + 2047];
              const float sv = silu_f(sacc[mt][nt][r] + bias);
              tb[r] = f2bf((dd0 + r <= 0) ? sv : 0.f);
            }
          } else {
            #pragma unroll
            for (int r=0;r<4;r++){
              const float bias = pwl[dd0 + r + 2047];
              tb[r] = f2bf(silu_f(sacc[mt][nt][r] + bias));
            }
          }
          ushort4 o;
          o.x=*(unsigned short*)&tb[0]; o.y=*(unsigned short*)&tb[1];
          o.z=*(unsigned short*)&tb[2]; o.w=*(unsigned short*)&tb[3];
          *(ushort4*)&Pl[wave][(mt*16 + l16)*72 + nt*16 + quad*4] = o;
        }
      }

      // O += P @ V: pf from Pl (A-frag), vf from vt global (B-frag: d=nt*16+l16, s contiguous)
      #pragma unroll
      for (int ks=0;ks<2;ks++){
        bf16x8 pf0 = *(const bf16x8*)&Pl[wave][(l16     )*72 + ks*32 + quad*8];
        bf16x8 pf1 = *(const bf16x8*)&Pl[wave][(16 + l16)*72 + ks*32 + quad*8];
        #pragma unroll
        for (int nt=0;nt<4;nt++){
          bf16x8 vf = *(const bf16x8*)(vgb + (nt*16 + l16)*SEQ + k0 + ks*32 + quad*8);
          oacc[0][nt] = mfma16(pf0, vf, oacc[0][nt]);
          oacc[1][nt] = mfma16(pf1, vf, oacc[1][nt]);
        }
      }
    }

    // write partial O (fp32; u-mult fused into lnorm)
    #pragma unroll
    for (int mt=0;mt<2;mt++){
      const int qrow = q0 + wave*32 + mt*16 + quad*4;
      #pragma unroll
      for (int nt=0;nt<4;nt++){
        const int c = hh*HD + nt*16 + l16;
        #pragma unroll
        for (int r=0;r<4;r++){
          yp[(b*SEQ + qrow + r)*DIM + c] = oacc[mt][nt][r];
        }
      }
    }
  }
}

// ---------------- fused: l1 = LN((y0 + y1) * u) ----------------
__global__ __launch_bounds__(256) void lnorm_fuse(
    const float* __restrict__ ya, const float* __restrict__ yb,
    const bf16* __restrict__ h, const float* __restrict__ g,
    const float* __restrict__ be, bf16* __restrict__ out)
{
  const int row = blockIdx.x;
  const int tid = threadIdx.x, wave = tid>>6, lane = tid&63;
  const int c0 = tid*4;
  const float4 a  = *(const float4*)(ya + row*DIM + c0);
  const float4 bb = *(const float4*)(yb + row*DIM + c0);
  const ushort4 uu = *(const ushort4*)((const unsigned short*)h + row*D4 + c0);
  float v[4];
  {
    bf16 u0,u1,u2,u3;
    *(unsigned short*)&u0 = uu.x; *(unsigned short*)&u1 = uu.y;
    *(unsigned short*)&u2 = uu.z; *(unsigned short*)&u3 = uu.w;
    v[0] = (a.x + bb.x) * bf2f(u0);
    v[1] = (a.y + bb.y) * bf2f(u1);
    v[2] = (a.z + bb.z) * bf2f(u2);
    v[3] = (a.w + bb.w) * bf2f(u3);
  }
  float s = 0.f, ss = 0.f;
  #pragma unroll
  for (int j=0;j<4;j++){ s += v[j]; ss += v[j]*v[j]; }
  #pragma unroll
  for (int off=32; off>0; off>>=1){
    s  += __shfl_down(s, off);
    ss += __shfl_down(ss, off);
  }
  __shared__ float red[8];
  if (lane==0){ red[wave] = s; red[4+wave] = ss; }
  __syncthreads();
  s  = red[0]+red[1]+red[2]+red[3];
  ss = red[4]+red[5]+red[6]+red[7];
  const float mu   = s * (1.f/DIM);
  const float var  = ss * (1.f/DIM) - mu*mu;
  const float rstd = rsqrtf(var + 1e-5f);
  #pragma unroll
  for (int j=0;j<4;j++){
    const int c = c0 + j;
    out[row*DIM + c] = f2bf((v[j]-mu)*rstd*g[c] + be[c]);
  }
}

// ---------------- row layernorm over D=1024 (fp32 in, fp32 out) ----------------
__global__ __launch_bounds__(256) void lnorm2k(const float* __restrict__ in,
    const float* __restrict__ g, const float* __restrict__ be, float* __restrict__ out)
{
  const int row = blockIdx.x;
  const int tid = threadIdx.x, wave = tid>>6, lane = tid&63;
  const int c0 = tid*4;
  const float4 a = *(const float4*)(in + row*DIM + c0);
  float v[4] = {a.x, a.y, a.z, a.w};
  float s = 0.f, ss = 0.f;
  #pragma unroll
  for (int j=0;j<4;j++){ s += v[j]; ss += v[j]*v[j]; }
  #pragma unroll
  for (int off=32; off>0; off>>=1){
    s  += __shfl_down(s, off);
    ss += __shfl_down(ss, off);
  }
  __shared__ float red[8];
  if (lane==0){ red[wave] = s; red[4+wave] = ss; }
  __syncthreads();
  s  = red[0]+red[1]+red[2]+red[3];
  ss = red[4]+red[5]+red[6]+red[7];
  const float mu   = s * (1.f/DIM);
  const float var  = ss * (1.f/DIM) - mu*mu;
  const float rstd = rsqrtf(var + 1e-5f);
  #pragma unroll
  for (int j=0;j<4;j++){
    const int c = c0 + j;
    out[row*DIM + c] = (v[j]-mu)*rstd*g[c] + be[c];
  }
}

extern "C" void kernel_launch(void* const* d_in, const int* in_sizes, int n_in,
                              void* d_out, int out_size, void* d_ws, size_t ws_size,
                              hipStream_t stream)
{
  const float* x   = (const float*)d_in[0];
  const float* w1  = (const float*)d_in[2];
  const float* b1  = (const float*)d_in[3];
  const float* w2  = (const float*)d_in[4];
  const float* b2  = (const float*)d_in[5];
  const float* g1  = (const float*)d_in[6];
  const float* be1 = (const float*)d_in[7];
  const float* g2  = (const float*)d_in[8];
  const float* be2 = (const float*)d_in[9];
  const float* pw  = (const float*)d_in[10];

  char* ws = (char*)d_ws;
  bf16*  h   = (bf16*)(ws);                 // [0,32M)   silu(f1) u|q|k|v
  bf16*  vt  = (bf16*)(ws + (32u<<20));     // [32,40M)  v transposed
  float* y0  = (float*)(ws + (40u<<20));    // [40,56M)  O partial even
  float* y1  = (float*)(ws + (56u<<20));    // [56,72M)  O partial odd
  bf16*  xb  = (bf16*)(ws + (72u<<20));     // [72,80M)
  bf16*  w1b = (bf16*)(ws + (80u<<20));     // [80,88M)
  bf16*  w2b = (bf16*)(ws + (88u<<20));     // [88,90M)
  bf16*  l1  = (bf16*)(ws + (32u<<20));     // reuses vt (dead after attn)
  float* z   = (float*)(ws + (40u<<20));    // reuses y0 (dead after lnorm_fuse)

  const int NX  = BN*SEQ*DIM;
  const int NW1 = 4*DIM*DIM;
  const int NW2 = DIM*DIM;
  f2bk3<<<dim3((NX+NW1+NW2)/1024), dim3(256), 0, stream>>>(x, xb, NX, w1, w1b, NW1, w2, w2b);

  gemm_bt<4096><<<dim3(1024), dim3(256), 0, stream>>>(xb, w1b, b1, h, vt);
  attn<<<dim3(512), dim3(256), 0, stream>>>(h, vt, pw, y0, y1);
  lnorm_fuse<<<dim3(4096), dim3(256), 0, stream>>>(y0, y1, h, g1, be1, l1);
  gemm_bt2<<<dim3(512), dim3(256), 0, stream>>>(l1, w2b, b2, x, z);
  lnorm2k<<<dim3(4096), dim3(256), 0, stream>>>(z, g2, be2, (float*)d_out);
}

// Round 10
// 256.145 us; speedup vs baseline: 1.0405x; 1.0405x over previous
//
#include <hip/hip_runtime.h>
#include <hip/hip_bf16.h>

#define BN   2
#define SEQ  2048
#define DIM  1024
#define NH   16
#define HD   64
#define D4   4096
#define MAXS 4096

using bf16 = __hip_bfloat16;
typedef __bf16 bf16x8 __attribute__((ext_vector_type(8)));
typedef float  f32x4  __attribute__((ext_vector_type(4)));

__device__ __forceinline__ float bf2f(bf16 v){ return __bfloat162float(v); }
__device__ __forceinline__ bf16  f2bf(float v){ return __float2bfloat16(v); }
__device__ __forceinline__ float silu_f(float v){
  const float e = __expf(-v);
  return v * __builtin_amdgcn_rcpf(1.f + e);
}

__device__ __forceinline__ void async16(void* lds, const void* g){
  __builtin_amdgcn_global_load_lds((const __attribute__((address_space(1))) void*)g,
                                   (__attribute__((address_space(3))) void*)lds, 16, 0, 0);
}
__device__ __forceinline__ f32x4 mfma16(bf16x8 a, bf16x8 b, f32x4 c){
  return __builtin_amdgcn_mfma_f32_16x16x32_bf16(a, b, c, 0, 0, 0);
}

// ---------------- fp32 -> bf16 convert (3 arrays, 1 launch) ----------------
__global__ __launch_bounds__(256) void f2bk3(
    const float* __restrict__ a, bf16* __restrict__ ao, int na,
    const float* __restrict__ b, bf16* __restrict__ bo, int nb,
    const float* __restrict__ c, bf16* __restrict__ co)
{
  int i = (blockIdx.x * 256 + threadIdx.x) * 4;
  const float* in; bf16* out;
  if (i < na){ in = a; out = ao; }
  else if (i < na + nb){ in = b; out = bo; i -= na; }
  else { in = c; out = co; i -= na + nb; }
  const float4 v = *(const float4*)(in + i);
  bf16 t0 = f2bf(v.x), t1 = f2bf(v.y), t2 = f2bf(v.z), t3 = f2bf(v.w);
  ushort4 o;
  o.x = *(unsigned short*)&t0; o.y = *(unsigned short*)&t1;
  o.z = *(unsigned short*)&t2; o.w = *(unsigned short*)&t3;
  *(ushort4*)((unsigned short*)out + i) = o;
}

// ---------------- GEMM1 (non-v tiles): C^T orientation, BK=64 ----------------
// C = silu(A @ W^T + bias) for n0 in [0, 3072). acc[nt][mt] holds C^T so a lane's
// 4 acc elems are 4 consecutive OUTPUT COLUMNS -> ushort4 stores.
// LDS rows 64 elems = 8 groups of 16B, group-slot XOR-swizzled by row&7.
__global__ __launch_bounds__(256) void gemm1_ct(
    const bf16* __restrict__ A, const bf16* __restrict__ W,
    const float* __restrict__ bias, bf16* __restrict__ outb)
{
  constexpr int K = DIM;
  const int m0 = (int)(blockIdx.x / 24) * 128;
  const int n0 = (int)(blockIdx.x % 24) * 128;
  __shared__ bf16 Al[128*64];
  __shared__ bf16 Bl[128*64];
  const int tid = threadIdx.x, wave = tid>>6, lane = tid&63;
  const int quad = lane>>4, l16 = lane&15;
  const int wm = (wave>>1)*64, wn = (wave&1)*64;
  const int srow = wave*8 + (lane>>3);
  const int sg   = ((lane&7) ^ ((lane>>3)&7)) * 8;

  f32x4 acc[4][4];
  #pragma unroll
  for (int i=0;i<4;i++)
    #pragma unroll
    for (int j=0;j<4;j++) acc[i][j] = (f32x4){0.f,0.f,0.f,0.f};

  const bf16* aB = A + m0*K;
  const bf16* wB = W + n0*K;

  for (int k0 = 0; k0 < K; k0 += 64){
    #pragma unroll
    for (int s=0;s<4;s++){
      async16(&Al[(s*32 + wave*8)*64], aB + (s*32 + srow)*K + k0 + sg);
      async16(&Bl[(s*32 + wave*8)*64], wB + (s*32 + srow)*K + k0 + sg);
    }
    __syncthreads();
    #pragma unroll
    for (int ks=0;ks<2;ks++){
      bf16x8 af[4], bv[4];
      #pragma unroll
      for (int mt=0;mt<4;mt++) af[mt] = *(const bf16x8*)&Al[(wm+mt*16+l16)*64 + ((ks*4+quad) ^ (l16&7))*8];
      #pragma unroll
      for (int nt=0;nt<4;nt++) bv[nt] = *(const bf16x8*)&Bl[(wn+nt*16+l16)*64 + ((ks*4+quad) ^ (l16&7))*8];
      #pragma unroll
      for (int nt=0;nt<4;nt++)
        #pragma unroll
        for (int mt=0;mt<4;mt++)
          acc[nt][mt] = mfma16(bv[nt], af[mt], acc[nt][mt]);   // A=W, B=x -> C^T
    }
    __syncthreads();
  }

  #pragma unroll
  for (int nt=0;nt<4;nt++){
    const int n = n0 + wn + nt*16 + quad*4;
    const float4 b4 = *(const float4*)&bias[n];
    #pragma unroll
    for (int mt=0;mt<4;mt++){
      const int m = m0 + wm + mt*16 + l16;
      bf16 t0 = f2bf(silu_f(acc[nt][mt][0] + b4.x));
      bf16 t1 = f2bf(silu_f(acc[nt][mt][1] + b4.y));
      bf16 t2 = f2bf(silu_f(acc[nt][mt][2] + b4.z));
      bf16 t3 = f2bf(silu_f(acc[nt][mt][3] + b4.w));
      ushort4 o;
      o.x=*(unsigned short*)&t0; o.y=*(unsigned short*)&t1;
      o.z=*(unsigned short*)&t2; o.w=*(unsigned short*)&t3;
      *(ushort4*)&outb[m*D4 + n] = o;
    }
  }
}

// ---------------- GEMM1 (v tiles): normal orientation, BK=64, transposed vt store ----------------
__global__ __launch_bounds__(256) void gemm1_v(
    const bf16* __restrict__ A, const bf16* __restrict__ W,
    const float* __restrict__ bias, bf16* __restrict__ vt)
{
  constexpr int K = DIM;
  const int m0 = (int)(blockIdx.x >> 3) * 128;
  const int n0 = 3*DIM + (int)(blockIdx.x & 7) * 128;
  __shared__ bf16 Al[128*64];
  __shared__ bf16 Bl[128*64];
  const int tid = threadIdx.x, wave = tid>>6, lane = tid&63;
  const int quad = lane>>4, l16 = lane&15;
  const int wm = (wave>>1)*64, wn = (wave&1)*64;
  const int srow = wave*8 + (lane>>3);
  const int sg   = ((lane&7) ^ ((lane>>3)&7)) * 8;

  f32x4 acc[4][4];
  #pragma unroll
  for (int i=0;i<4;i++)
    #pragma unroll
    for (int j=0;j<4;j++) acc[i][j] = (f32x4){0.f,0.f,0.f,0.f};

  const bf16* aB = A + m0*K;
  const bf16* wB = W + n0*K;

  for (int k0 = 0; k0 < K; k0 += 64){
    #pragma unroll
    for (int s=0;s<4;s++){
      async16(&Al[(s*32 + wave*8)*64], aB + (s*32 + srow)*K + k0 + sg);
      async16(&Bl[(s*32 + wave*8)*64], wB + (s*32 + srow)*K + k0 + sg);
    }
    __syncthreads();
    #pragma unroll
    for (int ks=0;ks<2;ks++){
      bf16x8 af[4], bv[4];
      #pragma unroll
      for (int mt=0;mt<4;mt++) af[mt] = *(const bf16x8*)&Al[(wm+mt*16+l16)*64 + ((ks*4+quad) ^ (l16&7))*8];
      #pragma unroll
      for (int nt=0;nt<4;nt++) bv[nt] = *(const bf16x8*)&Bl[(wn+nt*16+l16)*64 + ((ks*4+quad) ^ (l16&7))*8];
      #pragma unroll
      for (int mt=0;mt<4;mt++)
        #pragma unroll
        for (int nt=0;nt<4;nt++)
          acc[mt][nt] = mfma16(af[mt], bv[nt], acc[mt][nt]);
    }
    __syncthreads();
  }

  #pragma unroll
  for (int mt=0;mt<4;mt++){
    #pragma unroll
    for (int nt=0;nt<4;nt++){
      const int row = m0 + wm + mt*16 + quad*4;
      const int colg = n0 + wn + nt*16 + l16;
      const float bvv = bias[colg];
      const int col = colg - 3*DIM;
      const int hh = col >> 6, d = col & 63;
      const int bb = row >> 11, sl = row & 2047;
      float v0 = silu_f(acc[mt][nt][0] + bvv);
      float v1 = silu_f(acc[mt][nt][1] + bvv);
      float v2 = silu_f(acc[mt][nt][2] + bvv);
      float v3 = silu_f(acc[mt][nt][3] + bvv);
      bf16 t0=f2bf(v0), t1=f2bf(v1), t2=f2bf(v2), t3=f2bf(v3);
      ushort4 o;
      o.x=*(unsigned short*)&t0; o.y=*(unsigned short*)&t1;
      o.z=*(unsigned short*)&t2; o.w=*(unsigned short*)&t3;
      *(ushort4*)&vt[((bb*NH + hh)*HD + d)*SEQ + sl] = o;
    }
  }
}

// ---------------- GEMM2: z = A @ W^T + bias + resid, C^T orientation, BK=64, float4 out ----------------
__global__ __launch_bounds__(256) void gemm2_ct(
    const bf16* __restrict__ A, const bf16* __restrict__ W,
    const float* __restrict__ bias, const float* __restrict__ resid,
    float* __restrict__ outf)
{
  constexpr int K = DIM, NTOT = DIM;
  const int m0 = (int)(blockIdx.x >> 4) * 128;
  const int n0 = (int)(blockIdx.x & 15) * 64;
  __shared__ bf16 Al[128*64];
  __shared__ bf16 Bl[64*64];
  const int tid = threadIdx.x, wave = tid>>6, lane = tid&63;
  const int quad = lane>>4, l16 = lane&15;
  const int srow = wave*8 + (lane>>3);
  const int sg   = ((lane&7) ^ ((lane>>3)&7)) * 8;

  f32x4 acc[4][2];   // [nt][mt] = C^T
  #pragma unroll
  for (int i=0;i<4;i++)
    #pragma unroll
    for (int j=0;j<2;j++) acc[i][j] = (f32x4){0.f,0.f,0.f,0.f};

  const bf16* aB = A + m0*K;
  const bf16* wB = W + n0*K;

  for (int k0 = 0; k0 < K; k0 += 64){
    #pragma unroll
    for (int s=0;s<4;s++)
      async16(&Al[(s*32 + wave*8)*64], aB + (s*32 + srow)*K + k0 + sg);
    #pragma unroll
    for (int s=0;s<2;s++)
      async16(&Bl[(s*32 + wave*8)*64], wB + (s*32 + srow)*K + k0 + sg);
    __syncthreads();
    #pragma unroll
    for (int ks=0;ks<2;ks++){
      bf16x8 af[2], bv[4];
      #pragma unroll
      for (int mt=0;mt<2;mt++) af[mt] = *(const bf16x8*)&Al[(wave*32+mt*16+l16)*64 + ((ks*4+quad) ^ (l16&7))*8];
      #pragma unroll
      for (int nt=0;nt<4;nt++) bv[nt] = *(const bf16x8*)&Bl[(nt*16+l16)*64 + ((ks*4+quad) ^ (l16&7))*8];
      #pragma unroll
      for (int nt=0;nt<4;nt++)
        #pragma unroll
        for (int mt=0;mt<2;mt++)
          acc[nt][mt] = mfma16(bv[nt], af[mt], acc[nt][mt]);
    }
    __syncthreads();
  }

  #pragma unroll
  for (int nt=0;nt<4;nt++){
    const int n = n0 + nt*16 + quad*4;
    const float4 b4 = *(const float4*)&bias[n];
    #pragma unroll
    for (int mt=0;mt<2;mt++){
      const int m = m0 + wave*32 + mt*16 + l16;
      const float4 r4 = *(const float4*)&resid[m*NTOT + n];
      float4 o;
      o.x = acc[nt][mt][0] + b4.x + r4.x;
      o.y = acc[nt][mt][1] + b4.y + r4.y;
      o.z = acc[nt][mt][2] + b4.z + r4.z;
      o.w = acc[nt][mt][3] + b4.w + r4.w;
      *(float4*)&outf[m*NTOT + n] = o;
    }
  }
}

// ---------------- attention (R5 best-measured variant) ----------------
// block = (b, head, q-tile PAIR {qp,31-qp}); grid 512 = 2 blocks/CU; bid%8 = XCD group.
__global__ __launch_bounds__(256) void attn(
    const bf16* __restrict__ h, const bf16* __restrict__ vt,
    const float* __restrict__ pw, bf16* __restrict__ y)
{
  const int bid = blockIdx.x;
  const int g  = (bid & 7) + ((bid >> 7) << 3);
  const int qp = (bid >> 3) & 15;
  const int hh = g & 15, b = g >> 4;
  __shared__ bf16 Kl[128*64];
  __shared__ bf16 Vl[64*128];
  __shared__ bf16 Pl[4][16*136];
  __shared__ float pwl[256];
  const int tid = threadIdx.x, wave = tid>>6, lane = tid&63;
  const int quad = lane>>4, l16 = lane&15;

  const bf16* kgb = h + b*SEQ*D4 + 2*DIM + hh*HD;
  const bf16* vgb = vt + (b*NH + hh)*HD*SEQ;
  const int krow8 = lane>>3;
  const int kgo   = ((lane&7) ^ krow8) * 8;
  const int vrow4 = lane>>4;

  #pragma unroll
  for (int pass = 0; pass < 2; ++pass){
    const int qt = pass ? (31 - qp) : qp;
    const int q0 = qt * 64;

    const bf16* qbase = h + (b*SEQ + q0 + wave*16 + l16)*D4 + DIM + hh*HD;
    bf16x8 qf[2];
    qf[0] = *(const bf16x8*)(qbase + quad*8);
    qf[1] = *(const bf16x8*)(qbase + 32 + quad*8);

    f32x4 oacc[4];
    #pragma unroll
    for (int nt=0;nt<4;nt++) oacc[nt] = (f32x4){0.f,0.f,0.f,0.f};

    const int kmax = q0 + 64;
    for (int k0 = 0; k0 < kmax; k0 += 128){
      #pragma unroll
      for (int t=0;t<4;t++)
        async16(&Kl[(wave*32 + t*8)*64], kgb + (k0 + wave*32 + t*8 + krow8)*D4 + kgo);
      #pragma unroll
      for (int t=0;t<4;t++){
        const int vg = ((lane&15) ^ (t*4 + vrow4)) * 8;
        async16(&Vl[(wave*16 + t*4)*128], vgb + (wave*16 + t*4 + vrow4)*SEQ + k0 + vg);
      }
      const int W0 = MAXS - 1 + k0 - q0 - 63;
      if (wave == 0) async16(&pwl[0], pw + W0 + lane*4);
      __syncthreads();

      f32x4 sacc[8];
      #pragma unroll
      for (int nt=0;nt<8;nt++) sacc[nt] = (f32x4){0.f,0.f,0.f,0.f};
      #pragma unroll
      for (int ks=0;ks<2;ks++){
        #pragma unroll
        for (int nt=0;nt<8;nt++){
          bf16x8 kf = *(const bf16x8*)&Kl[(nt*16 + l16)*64 + ((ks*4 + quad) ^ (l16&7))*8];
          sacc[nt] = mfma16(qf[ks], kf, sacc[nt]);
        }
      }
      const int li = wave*16 + quad*4;
      const int dq = q0 - k0;
      #pragma unroll
      for (int nt=0;nt<8;nt++){
        const int lj = nt*16 + l16;
        #pragma unroll
        for (int r=0;r<4;r++){
          const float bias = pwl[lj - (li+r) + 63];
          const float sv = silu_f(sacc[nt][r] + bias);
          const float v = (lj - (li+r) <= dq) ? sv : 0.f;
          Pl[wave][(quad*4+r)*136 + lj] = f2bf(v);
        }
      }

      #pragma unroll
      for (int ks=0;ks<4;ks++){
        bf16x8 pf = *(const bf16x8*)&Pl[wave][l16*136 + ks*32 + quad*8];
        #pragma unroll
        for (int nt=0;nt<4;nt++){
          bf16x8 vf = *(const bf16x8*)&Vl[(nt*16 + l16)*128 + ((ks*4 + quad) ^ l16)*8];
          oacc[nt] = mfma16(pf, vf, oacc[nt]);
        }
      }
      __syncthreads();
    }

    const int qrow = q0 + wave*16 + quad*4;
    #pragma unroll
    for (int nt=0;nt<4;nt++){
      const int c = hh*HD + nt*16 + l16;
      #pragma unroll
      for (int r=0;r<4;r++){
        const int srow = b*SEQ + qrow + r;
        const float uu = bf2f(h[srow*D4 + c]);
        y[srow*DIM + c] = f2bf(oacc[nt][r] * uu);
      }
    }
    __syncthreads();
  }
}

// ---------------- row layernorm over D=1024 ----------------
template<bool FP32IN, bool FP32OUT>
__global__ __launch_bounds__(256) void lnorm(const void* __restrict__ in,
    const float* __restrict__ g, const float* __restrict__ be, void* __restrict__ out)
{
  const int row = blockIdx.x;
  const int tid = threadIdx.x, wave = tid>>6, lane = tid&63;
  const int c0 = tid*4;
  float v[4];
  if (FP32IN){
    const float* p = (const float*)in + row*DIM + c0;
    #pragma unroll
    for (int j=0;j<4;j++) v[j] = p[j];
  } else {
    const bf16* p = (const bf16*)in + row*DIM + c0;
    #pragma unroll
    for (int j=0;j<4;j++) v[j] = bf2f(p[j]);
  }
  float s = 0.f, ss = 0.f;
  #pragma unroll
  for (int j=0;j<4;j++){ s += v[j]; ss += v[j]*v[j]; }
  #pragma unroll
  for (int off=32; off>0; off>>=1){
    s  += __shfl_down(s, off);
    ss += __shfl_down(ss, off);
  }
  __shared__ float red[8];
  if (lane==0){ red[wave] = s; red[4+wave] = ss; }
  __syncthreads();
  s  = red[0]+red[1]+red[2]+red[3];
  ss = red[4]+red[5]+red[6]+red[7];
  const float mu   = s * (1.f/DIM);
  const float var  = ss * (1.f/DIM) - mu*mu;
  const float rstd = rsqrtf(var + 1e-5f);
  #pragma unroll
  for (int j=0;j<4;j++){
    const int c = c0 + j;
    const float o = (v[j]-mu)*rstd*g[c] + be[c];
    if (FP32OUT) ((float*)out)[row*DIM + c] = o;
    else         ((bf16*)out)[row*DIM + c] = f2bf(o);
  }
}

extern "C" void kernel_launch(void* const* d_in, const int* in_sizes, int n_in,
                              void* d_out, int out_size, void* d_ws, size_t ws_size,
                              hipStream_t stream)
{
  const float* x   = (const float*)d_in[0];
  const float* w1  = (const float*)d_in[2];
  const float* b1  = (const float*)d_in[3];
  const float* w2  = (const float*)d_in[4];
  const float* b2  = (const float*)d_in[5];
  const float* g1  = (const float*)d_in[6];
  const float* be1 = (const float*)d_in[7];
  const float* g2  = (const float*)d_in[8];
  const float* be2 = (const float*)d_in[9];
  const float* pw  = (const float*)d_in[10];

  char* ws = (char*)d_ws;
  bf16*  h   = (bf16*)(ws);                 // [0,32M)   u|q|k (v region unused)
  bf16*  vt  = (bf16*)(ws + (32u<<20));     // [32,40M)  v transposed
  bf16*  y   = (bf16*)(ws + (40u<<20));     // [40,48M)  attn*u, bf16
  bf16*  xb  = (bf16*)(ws + (48u<<20));     // [48,56M)
  bf16*  w1b = (bf16*)(ws + (56u<<20));     // [56,64M)
  bf16*  w2b = (bf16*)(ws + (64u<<20));     // [64,66M)
  bf16*  l1  = (bf16*)(ws + (66u<<20));     // [66,74M)
  float* z   = (float*)(ws + (74u<<20));    // [74,90M)

  const int NX  = BN*SEQ*DIM;
  const int NW1 = 4*DIM*DIM;
  const int NW2 = DIM*DIM;
  f2bk3<<<dim3((NX+NW1+NW2)/1024), dim3(256), 0, stream>>>(x, xb, NX, w1, w1b, NW1, w2, w2b);

  gemm1_ct<<<dim3(768), dim3(256), 0, stream>>>(xb, w1b, b1, h);
  gemm1_v <<<dim3(256), dim3(256), 0, stream>>>(xb, w1b, b1, vt);
  attn<<<dim3(512), dim3(256), 0, stream>>>(h, vt, pw, y);
  lnorm<false,false><<<dim3(4096), dim3(256), 0, stream>>>(y, g1, be1, l1);
  gemm2_ct<<<dim3(512), dim3(256), 0, stream>>>(l1, w2b, b2, x, z);
  lnorm<true,true><<<dim3(4096), dim3(256), 0, stream>>>(z, g2, be2, d_out);
}